// Round 2
// baseline (1178.134 us; speedup 1.0000x reference)
//
#include <hip/hip_runtime.h>
#include <math.h>

// Problem: B=4, C=192, H=W=256 -> N=65536, heads=8, Ch=24
// Decomposition:
//   G_bh   = q_h k_h^T (raw, unnormalized)         [K1]
//   ssq    = per-row sum of squares of q,k         [K1]
//   attn   = softmax(G * temp / (|q||k|))          [K2a]
//   M_b    = W_out * blockdiag(attn)               [K2a]
//   P_b    = M_b * W_v                             [K2b]
//   out    = P_b * x_b                             [K3]
//
// ws layout (floats):
//   gpart : 16 slices * 4 b * 4608  = 294912
//   ssq   : 4 * 384                 = 1536      (q rows 0..191, k rows 192..383)
//   M     : 4 * 192 * 192           = 147456
//   P     : 4 * 192 * 192           = 147456

#define L2EPS 1e-12f

// ---------------------------------------------------------------- K1
// grid (256, 4), 256 threads. Each block: 256 columns (8 tiles of 32) of batch b.
// Per tile: Q,K (384x32) = [Wq;Wk](384x192) @ Xtile(192x32), staged via LDS,
// then sumsq + per-head Gram accumulation.
__global__ __launch_bounds__(256, 2) void k1_qk_gram(
    const float* __restrict__ x, const float* __restrict__ wqkv,
    float* __restrict__ gpart, float* __restrict__ ssq)
{
  __shared__ float Xs[16][32];     // x k-chunk [k][n]
  __shared__ float Ws[16][388];    // W chunk transposed [k][r], pad 4 for b128 align
  __shared__ float Qs[32][196];    // Q tile [n][r], stride 196 (16B aligned)
  __shared__ float Ks[32][196];

  const int t = threadIdx.x;
  const int b = blockIdx.y;
  const int cb = blockIdx.x;
  const int cg = t & 7;            // 8 col groups * 4 cols = 32
  const int rowg = t >> 3;         // 32 row groups * 12 rows = 384
  const int rowbase = rowg * 12;

  // gram mapping: 8 heads * (8 ctiles of 3) * (4 dtiles of 6) = 256 threads
  const int ghead = t >> 5;
  const int gc0 = ((t & 31) >> 2) * 3;
  const int gd0 = (t & 3) * 6;

  float gacc[3][6];
#pragma unroll
  for (int i = 0; i < 3; ++i)
#pragma unroll
    for (int j = 0; j < 6; ++j) gacc[i][j] = 0.f;
  float sq0 = 0.f, sq1 = 0.f;

  const float* xb = x + (size_t)b * 192 * 65536;
  const float4* wq4 = (const float4*)wqkv;

  for (int tile = 0; tile < 8; ++tile) {
    const int n0 = (cb * 8 + tile) * 32;
    float acc[12][4];
#pragma unroll
    for (int i = 0; i < 12; ++i)
#pragma unroll
      for (int j = 0; j < 4; ++j) acc[i][j] = 0.f;

    for (int kb = 0; kb < 12; ++kb) {
      if (t < 128) {
        const int kl = t >> 3, n4 = t & 7;
        *(float4*)&Xs[kl][n4 * 4] =
            *(const float4*)&xb[(size_t)(kb * 16 + kl) * 65536 + n0 + n4 * 4];
      }
#pragma unroll
      for (int i = 0; i < 6; ++i) {          // 384 rows * 4 float4 = 1536 f4
        const int e4 = t + i * 256;
        const int r = e4 >> 2, kq = e4 & 3;
        const float4 w = wq4[r * 48 + kb * 4 + kq];
        Ws[kq * 4 + 0][r] = w.x; Ws[kq * 4 + 1][r] = w.y;
        Ws[kq * 4 + 2][r] = w.z; Ws[kq * 4 + 3][r] = w.w;
      }
      __syncthreads();
#pragma unroll
      for (int k = 0; k < 16; ++k) {
        const float4 xv = *(const float4*)&Xs[k][cg * 4];
        const float xa[4] = {xv.x, xv.y, xv.z, xv.w};
#pragma unroll
        for (int i3 = 0; i3 < 3; ++i3) {
          const float4 wv = *(const float4*)&Ws[k][rowbase + i3 * 4];
          const float wa[4] = {wv.x, wv.y, wv.z, wv.w};
#pragma unroll
          for (int ii = 0; ii < 4; ++ii)
#pragma unroll
            for (int j = 0; j < 4; ++j)
              acc[i3 * 4 + ii][j] += wa[ii] * xa[j];
        }
      }
      __syncthreads();
    }

    // register tile -> LDS, layout [n][r]
    {
      float* dst = (rowg < 16) ? &Qs[0][0] : &Ks[0][0];
      const int r = (rowg < 16) ? rowbase : (rowbase - 192);
#pragma unroll
      for (int j = 0; j < 4; ++j) {
        const int n = cg * 4 + j;
#pragma unroll
        for (int i3 = 0; i3 < 3; ++i3) {
          const float4 v = make_float4(acc[i3 * 4 + 0][j], acc[i3 * 4 + 1][j],
                                       acc[i3 * 4 + 2][j], acc[i3 * 4 + 3][j]);
          *(float4*)&dst[n * 196 + r + i3 * 4] = v;
        }
      }
    }
    __syncthreads();

    // sumsq: virtual rows t (all) and, for t<128, K rows 64..191
    {
      const float* src = (t < 192) ? &Qs[0][0] : &Ks[0][0];
      const int rr = (t < 192) ? t : (t - 192);
      float s = 0.f;
#pragma unroll
      for (int n = 0; n < 32; ++n) { const float q = src[n * 196 + rr]; s += q * q; }
      sq0 += s;
      if (t < 128) {
        const int r2 = t + 64;  // K rows 64..191
        float s2 = 0.f;
#pragma unroll
        for (int n = 0; n < 32; ++n) { const float q = Ks[n][r2]; s2 += q * q; }
        sq1 += s2;
      }
    }
    // gram: G[h][c][d] += sum_n Q[h*24+c][n] * K[h*24+d][n]
    {
      const int qb = ghead * 24 + gc0;
      const int kb2 = ghead * 24 + gd0;
#pragma unroll 4
      for (int n = 0; n < 32; ++n) {
        const float q0 = Qs[n][qb], q1 = Qs[n][qb + 1], q2 = Qs[n][qb + 2];
#pragma unroll
        for (int dj = 0; dj < 6; ++dj) {
          const float kv = Ks[n][kb2 + dj];
          gacc[0][dj] += q0 * kv;
          gacc[1][dj] += q1 * kv;
          gacc[2][dj] += q2 * kv;
        }
      }
    }
    __syncthreads();
  }

  // flush accumulators
  {
    const int slice = cb & 15;
    float* gdst = gpart + ((size_t)(slice * 4 + b)) * 4608 + ghead * 576;
#pragma unroll
    for (int i = 0; i < 3; ++i)
#pragma unroll
      for (int j = 0; j < 6; ++j)
        atomicAdd(&gdst[(gc0 + i) * 24 + (gd0 + j)], gacc[i][j]);
    atomicAdd(&ssq[b * 384 + t], sq0);
    if (t < 128) atomicAdd(&ssq[b * 384 + t + 256], sq1);
  }
}

// ---------------------------------------------------------------- K2a
// grid (8, 4): one block per (h, b). Reduce gpart -> G, softmax -> A,
// M[:, h*24..h*24+23] = W_out[:, h-block] @ A.
__global__ __launch_bounds__(256) void k2a_softmax_m(
    const float* __restrict__ gpart, const float* __restrict__ ssq,
    const float* __restrict__ temp, const float* __restrict__ wout,
    float* __restrict__ M)
{
  __shared__ float Gs[576];
  __shared__ float As[576];
  __shared__ float rqs[24], rks[24];
  const int t = threadIdx.x;
  const int h = blockIdx.x;
  const int b = blockIdx.y;

  for (int e = t; e < 576; e += 256) {
    float s = 0.f;
#pragma unroll
    for (int sl = 0; sl < 16; ++sl)
      s += gpart[((size_t)(sl * 4 + b)) * 4608 + h * 576 + e];
    Gs[e] = s;
  }
  if (t < 24)
    rqs[t] = 1.f / fmaxf(sqrtf(ssq[b * 384 + h * 24 + t]), L2EPS);
  else if (t >= 32 && t < 56)
    rks[t - 32] = 1.f / fmaxf(sqrtf(ssq[b * 384 + 192 + h * 24 + (t - 32)]), L2EPS);
  __syncthreads();

  if (t < 24) {
    const float tempv = temp[h];
    const float rqc = rqs[t];
    float v[24];
    float m = -1e30f;
#pragma unroll
    for (int d = 0; d < 24; ++d) {
      v[d] = Gs[t * 24 + d] * tempv * rqc * rks[d];
      m = fmaxf(m, v[d]);
    }
    float s = 0.f;
#pragma unroll
    for (int d = 0; d < 24; ++d) { v[d] = expf(v[d] - m); s += v[d]; }
    const float inv = 1.f / s;
#pragma unroll
    for (int d = 0; d < 24; ++d) As[t * 24 + d] = v[d] * inv;
  }
  __syncthreads();

  // M[o][h*24+j] = sum_i wout[o][h*24+i] * As[i][j]; 192*24 = 4608 = 256*18
#pragma unroll
  for (int u = 0; u < 18; ++u) {
    const int p = t + 256 * u;
    const int o = p / 24, j = p % 24;
    float s = 0.f;
#pragma unroll
    for (int i = 0; i < 24; ++i)
      s += wout[o * 192 + h * 24 + i] * As[i * 24 + j];
    M[((size_t)b * 192 + o) * 192 + h * 24 + j] = s;
  }
}

// ---------------------------------------------------------------- K2b
// grid (24, 4): P_b = M_b @ Wv  (192x192 @ 192x192), 8 rows per block.
// Each block owns 8 rows * 48 float4 = 384 outputs (NOT 1536 — that was the
// round-1 bug: ol ran to 31, reading Ms[] OOB and stomping other blocks' rows).
__global__ __launch_bounds__(256) void k2b_p(
    const float* __restrict__ M, const float* __restrict__ wqkv,
    float* __restrict__ P)
{
  __shared__ float Ms[8][192];
  const int t = threadIdx.x;
  const int r0 = blockIdx.x * 8;
  const int b = blockIdx.y;
  for (int e = t; e < 1536; e += 256)
    (&Ms[0][0])[e] = M[((size_t)b * 192 + r0) * 192 + e];
  __syncthreads();
  const float4* wv4 = (const float4*)(wqkv + 384 * 192);
#pragma unroll
  for (int u = 0; u < 2; ++u) {
    const int idx4 = t + 256 * u;
    if (idx4 < 384) {
      const int ol = idx4 / 48, c4 = idx4 % 48;
      float4 a = make_float4(0.f, 0.f, 0.f, 0.f);
      for (int c = 0; c < 192; ++c) {
        const float m = Ms[ol][c];
        const float4 w = wv4[c * 48 + c4];
        a.x += m * w.x; a.y += m * w.y; a.z += m * w.z; a.w += m * w.w;
      }
      ((float4*)P)[((size_t)b * 192 + r0 + ol) * 48 + c4] = a;
    }
  }
}

// ---------------------------------------------------------------- K3
// grid (1024, 4): out_b = P_b @ x_b. Block: 192 rows x 64 cols.
__global__ __launch_bounds__(256, 2) void k3_out(
    const float* __restrict__ P, const float* __restrict__ x,
    float* __restrict__ out)
{
  __shared__ float Xs[16][68];
  __shared__ float Ps[16][196];
  const int t = threadIdx.x;
  const int b = blockIdx.y;
  const int n0 = blockIdx.x * 64;
  const int cg = t & 15;          // 16 col groups * 4 = 64
  const int rowg = t >> 4;        // 16 row groups * 12 = 192
  const int rowbase = rowg * 12;
  const float* xb = x + (size_t)b * 192 * 65536;
  const float4* Pb4 = (const float4*)(P + (size_t)b * 36864);

  float acc[12][4];
#pragma unroll
  for (int i = 0; i < 12; ++i)
#pragma unroll
    for (int j = 0; j < 4; ++j) acc[i][j] = 0.f;

  for (int kb = 0; kb < 12; ++kb) {
    {
      const int kl = t >> 4, n4 = t & 15;
      *(float4*)&Xs[kl][n4 * 4] =
          *(const float4*)&xb[(size_t)(kb * 16 + kl) * 65536 + n0 + n4 * 4];
    }
#pragma unroll
    for (int i = 0; i < 3; ++i) {        // 192 rows * 4 f4 = 768 f4
      const int e4 = t + i * 256;
      const int r = e4 >> 2, kq = e4 & 3;
      const float4 w = Pb4[r * 48 + kb * 4 + kq];
      Ps[kq * 4 + 0][r] = w.x; Ps[kq * 4 + 1][r] = w.y;
      Ps[kq * 4 + 2][r] = w.z; Ps[kq * 4 + 3][r] = w.w;
    }
    __syncthreads();
#pragma unroll
    for (int k = 0; k < 16; ++k) {
      const float4 xv = *(const float4*)&Xs[k][cg * 4];
      const float xa[4] = {xv.x, xv.y, xv.z, xv.w};
#pragma unroll
      for (int i3 = 0; i3 < 3; ++i3) {
        const float4 wv = *(const float4*)&Ps[k][rowbase + i3 * 4];
        const float wa[4] = {wv.x, wv.y, wv.z, wv.w};
#pragma unroll
        for (int ii = 0; ii < 4; ++ii)
#pragma unroll
          for (int j = 0; j < 4; ++j)
            acc[i3 * 4 + ii][j] += wa[ii] * xa[j];
      }
    }
    __syncthreads();
  }
  float* ob = out + ((size_t)b * 192 + rowbase) * 65536 + n0 + cg * 4;
#pragma unroll
  for (int i = 0; i < 12; ++i)
    *(float4*)&ob[(size_t)i * 65536] =
        make_float4(acc[i][0], acc[i][1], acc[i][2], acc[i][3]);
}

// ---------------------------------------------------------------- launch
extern "C" void kernel_launch(void* const* d_in, const int* in_sizes, int n_in,
                              void* d_out, int out_size, void* d_ws, size_t ws_size,
                              hipStream_t stream) {
  const float* x    = (const float*)d_in[0];
  const float* wqkv = (const float*)d_in[1];
  const float* wout = (const float*)d_in[2];
  const float* temp = (const float*)d_in[3];
  float* out = (float*)d_out;

  float* ws    = (float*)d_ws;
  float* gpart = ws;               // 294912 floats
  float* ssq   = ws + 294912;      // 1536
  float* M     = ws + 296448;      // 147456
  float* P     = ws + 443904;      // 147456

  // zero the accumulators (gpart + ssq); ws is poisoned before every launch
  hipMemsetAsync(d_ws, 0, (size_t)296448 * sizeof(float), stream);

  k1_qk_gram<<<dim3(256, 4), 256, 0, stream>>>(x, wqkv, gpart, ssq);
  k2a_softmax_m<<<dim3(8, 4), 256, 0, stream>>>(gpart, ssq, temp, wout, M);
  k2b_p<<<dim3(24, 4), 256, 0, stream>>>(M, wqkv, P);
  k3_out<<<dim3(1024, 4), 256, 0, stream>>>(P, x, out);
}